// Round 11
// baseline (279.952 us; speedup 1.0000x reference)
//
#include <hip/hip_runtime.h>
#include <math.h>

#define AFWD 0.999f
#define ONE_MINUS_A (1.0f - 0.999f)
#define KCOEF (0.999f * (1.0f - 0.999f))
#define EPSV 1e-5f

typedef float floatx4 __attribute__((ext_vector_type(4)));

__device__ __forceinline__ void spin_on(int* p) {
  while (__hip_atomic_load(p, __ATOMIC_ACQUIRE, __HIP_MEMORY_SCOPE_AGENT) == 0)
    __builtin_amdgcn_s_sleep(8);
}

// ===========================================================================
// Single-dispatch hierarchical decoupled-lookback online normalization.
// Block (c = blockIdx/JG, j = blockIdx%JG); 256 threads x 4 cols = 1024 cols.
// Phase 1: chunk summary (B,T,S) in registers; publish + release statC.
//          Ticket per (super-chunk g, j): last of 16 arrivers composes the
//          16 chunk aggregates into a super-aggregate; release statG.
// Phase 2: spin ONLY on strict predecessors (statG[g'<g], statC siblings),
//          walk (m,var) through <=7 super + <=15 chunk apply-steps, then
//          replay the slab (L2/L3-hot from phase 1) and NT-store out.
// Composition algebra (proven R6/R10):
//   apply:   sum = S - 2*ceg*M*T + M^2*Sgg ; V' = A*V + KCOEF*sum ; M' = A*M+B
//   compose: S <- A*S + s2 - 2*ceg*B*t2 + Sgg*B^2 ; T <- T + t2 - G*B ;
//            B <- A*B + b2
// ===========================================================================
__global__ __launch_bounds__(256) void
lookback_cn(const float* __restrict__ x, const float* __restrict__ m,
            const float* __restrict__ var, float* __restrict__ out,
            float* __restrict__ aggB, float* __restrict__ aggS,
            float* __restrict__ aggT, float* __restrict__ supB,
            float* __restrict__ supS, float* __restrict__ supT,
            int* __restrict__ statC, int* __restrict__ statG,
            int* __restrict__ cntG,
            int L4, int CH, int JG, int SUB,
            float A, float c_eg, float Sgg, float G,
            float Asup, float c_sup, float Sggsup) {
  __shared__ int isLast;

  int b = blockIdx.x;
  int c = b / JG;
  int j = b % JG;
  int t = threadIdx.x;
  int col4 = j * 256 + t;
  int g = c / SUB;
  int r = c - g * SUB;

  const floatx4* xv = (const floatx4*)x;
  floatx4* aggB4 = (floatx4*)aggB;
  floatx4* aggS4 = (floatx4*)aggS;
  floatx4* aggT4 = (floatx4*)aggT;
  floatx4* supB4 = (floatx4*)supB;
  floatx4* supS4 = (floatx4*)supS;
  floatx4* supT4 = (floatx4*)supT;

  int base = c * CH * L4 + col4;

  // ---------------- phase 1: chunk summary ----------------
  float mu[4] = {0.f, 0.f, 0.f, 0.f};
  float sv[4] = {0.f, 0.f, 0.f, 0.f};
  float tv[4] = {0.f, 0.f, 0.f, 0.f};
#pragma unroll 4
  for (int i = 0; i < CH; ++i) {
    floatx4 v = xv[base + i * L4];
#pragma unroll
    for (int k = 0; k < 4; ++k) {
      float e = v[k] - mu[k];
      sv[k] = fmaf(AFWD, sv[k], e * e);
      tv[k] += e;
      mu[k] = fmaf(ONE_MINUS_A, e, mu[k]);
    }
  }
  {
    int o = c * L4 + col4;
    floatx4 ob = {mu[0], mu[1], mu[2], mu[3]};
    floatx4 os = {sv[0], sv[1], sv[2], sv[3]};
    floatx4 ot = {tv[0], tv[1], tv[2], tv[3]};
    aggB4[o] = ob;
    aggS4[o] = os;
    aggT4[o] = ot;
  }
  __threadfence();
  __syncthreads();
  if (t == 0) {
    __hip_atomic_store(&statC[c * JG + j], 1, __ATOMIC_RELEASE,
                       __HIP_MEMORY_SCOPE_AGENT);
    int old = __hip_atomic_fetch_add(&cntG[g * JG + j], 1, __ATOMIC_ACQ_REL,
                                     __HIP_MEMORY_SCOPE_AGENT);
    isLast = (old == SUB - 1);
  }
  __syncthreads();

  // ---------------- last arriver composes super-aggregate ----------------
  if (isLast) {
    float B[4] = {0.f, 0.f, 0.f, 0.f};
    float S[4] = {0.f, 0.f, 0.f, 0.f};
    float T[4] = {0.f, 0.f, 0.f, 0.f};
    for (int k = 0; k < SUB; ++k) {
      int o = (g * SUB + k) * L4 + col4;
      floatx4 b2 = aggB4[o];
      floatx4 s2 = aggS4[o];
      floatx4 t2 = aggT4[o];
#pragma unroll
      for (int q = 0; q < 4; ++q) {
        S[q] = fmaf(A, S[q],
                    fmaf(Sgg * B[q], B[q], fmaf(-2.0f * c_eg * B[q], t2[q], s2[q])));
        T[q] = fmaf(-G, B[q], T[q] + t2[q]);
        B[q] = fmaf(A, B[q], b2[q]);
      }
    }
    int o = g * L4 + col4;
    floatx4 ob = {B[0], B[1], B[2], B[3]};
    floatx4 os = {S[0], S[1], S[2], S[3]};
    floatx4 ot = {T[0], T[1], T[2], T[3]};
    supB4[o] = ob;
    supS4[o] = os;
    supT4[o] = ot;
    __threadfence();
    __syncthreads();
    if (t == 0)
      __hip_atomic_store(&statG[g * JG + j], 1, __ATOMIC_RELEASE,
                         __HIP_MEMORY_SCOPE_AGENT);
  }

  // ---------------- phase 2: wait on predecessors, walk, replay ----------
  if (t == 0) {
    for (int gg = 0; gg < g; ++gg) spin_on(&statG[gg * JG + j]);
    for (int cc = c - r; cc < c; ++cc) spin_on(&statC[cc * JG + j]);
  }
  __syncthreads();

  float M[4], V[4];
  {
    floatx4 m4 = ((const floatx4*)m)[col4];
    floatx4 v4 = ((const floatx4*)var)[col4];
#pragma unroll
    for (int k = 0; k < 4; ++k) { M[k] = m4[k]; V[k] = v4[k]; }
  }
  for (int gg = 0; gg < g; ++gg) {
    int o = gg * L4 + col4;
    floatx4 bb = supB4[o];
    floatx4 ss = supS4[o];
    floatx4 tt = supT4[o];
#pragma unroll
    for (int k = 0; k < 4; ++k) {
      float sum = fmaf(M[k] * M[k], Sggsup,
                       fmaf(-2.0f * c_sup * M[k], tt[k], ss[k]));
      V[k] = fmaf(Asup, V[k], KCOEF * sum);
      M[k] = fmaf(Asup, M[k], bb[k]);
    }
  }
  for (int cc = c - r; cc < c; ++cc) {
    int o = cc * L4 + col4;
    floatx4 bb = aggB4[o];
    floatx4 ss = aggS4[o];
    floatx4 tt = aggT4[o];
#pragma unroll
    for (int k = 0; k < 4; ++k) {
      float sum = fmaf(M[k] * M[k], Sgg,
                       fmaf(-2.0f * c_eg * M[k], tt[k], ss[k]));
      V[k] = fmaf(A, V[k], KCOEF * sum);
      M[k] = fmaf(A, M[k], bb[k]);
    }
  }

  {
    floatx4* ov = (floatx4*)out;
#pragma unroll 4
    for (int i = 0; i < CH; ++i) {
      floatx4 v = xv[base + i * L4];
      floatx4 oe;
#pragma unroll
      for (int k = 0; k < 4; ++k) {
        float d = v[k] - M[k];
        oe[k] = d * rsqrtf(V[k] + EPSV);
        V[k] = fmaf(AFWD, V[k], KCOEF * (d * d));
        M[k] = fmaf(ONE_MINUS_A, d, M[k]);
      }
      __builtin_nontemporal_store(oe, &ov[base + i * L4]);
    }
  }
}

extern "C" void kernel_launch(void* const* d_in, const int* in_sizes, int n_in,
                              void* d_out, int out_size, void* d_ws, size_t ws_size,
                              hipStream_t stream) {
  const float* x   = (const float*)d_in[0];
  const float* m   = (const float*)d_in[1];
  const float* var = (const float*)d_in[2];
  float* out = (float*)d_out;

  int L  = in_sizes[1];          // 4096
  int N  = in_sizes[0] / L;      // 8192
  int L4 = L / 4;
  int JG = L4 / 256;             // col-groups per chunk (4)

  int C = 128;
  while (C > 1 && ((N % C) != 0)) C >>= 1;
  int CH = N / C;
  int SUB = (C >= 16) ? 16 : C;
  int GS  = C / SUB;

  double a = 0.999;
  float A    = (float)pow(a, (double)CH);
  float c_eg = (float)pow(a, (double)(CH - 1));
  float Sgg  = (float)(pow(a, (double)(CH - 1)) * (1.0 - pow(a, (double)CH)) / (1.0 - a));
  float G    = (float)((1.0 - pow(a, (double)CH)) / (1.0 - a));
  double nS = (double)SUB * CH;
  float Asup   = (float)pow(a, nS);
  float c_sup  = (float)pow(a, nS - 1.0);
  float Sggsup = (float)(pow(a, nS - 1.0) * (1.0 - pow(a, nS)) / (1.0 - a));

  float* ws  = (float*)d_ws;
  size_t CL  = (size_t)C * L;
  size_t GL  = (size_t)GS * L;
  float* aggB = ws;
  float* aggS = ws + CL;
  float* aggT = ws + 2 * CL;
  float* supB = ws + 3 * CL;
  float* supS = supB + GL;
  float* supT = supB + 2 * GL;
  int*   statC = (int*)(supB + 3 * GL);
  int*   statG = statC + C * JG;
  int*   cntG  = statG + GS * JG;

  // Zero the flag/counter region each call (captured as a graph node, so
  // every replay re-initializes; ws is otherwise poison-tolerant).
  size_t flagBytes = (size_t)(C + 2 * GS) * JG * sizeof(int);
  hipMemsetAsync(statC, 0, flagBytes, stream);

  int gridBlocks = C * JG;   // 512
  lookback_cn<<<gridBlocks, 256, 0, stream>>>(
      x, m, var, out, aggB, aggS, aggT, supB, supS, supT, statC, statG, cntG,
      L4, CH, JG, SUB, A, c_eg, Sgg, G, Asup, c_sup, Sggsup);
}

// Round 12
// 86.010 us; speedup vs baseline: 3.2549x; 3.2549x over previous
//
#include <hip/hip_runtime.h>
#include <math.h>

#define AFWD 0.999f
#define ONE_MINUS_A (1.0f - 0.999f)
#define KCOEF (0.999f * (1.0f - 0.999f))
#define EPSV 1e-5f

typedef float floatx4 __attribute__((ext_vector_type(4)));

// ===========================================================================
// Column-split pipeline: A1 B1 [C1|A2] B2 C2  (5 dispatches).
// Columns are independent; halving the column range halves the per-phase L3
// footprint (x_half 67MB + out_half 67MB + scratch ~15MB < 256MB), so pass
// C's x re-read stays Infinity-Cache-resident instead of thrashing to HBM.
// C1 and A2 touch disjoint column halves with no mutual dependency -> fused
// into one dispatch (blocks [0,HB) do C1, blocks [HB,2HB) do A2).
// ===========================================================================

// ---- pass A body: chunk summaries (chunk-start M=0) over one col-half ----
__device__ __forceinline__ void
passA_body(const float* __restrict__ x, float* __restrict__ Bmu,
           float* __restrict__ See, float* __restrict__ Te,
           int L4, int L4h, int CH, int colOff, int ih) {
  int col4 = colOff + (ih % L4h);
  int c    = ih / L4h;
  const floatx4* xv = (const floatx4*)x;
  int base = c * CH * L4 + col4;

  float mu[4] = {0.f, 0.f, 0.f, 0.f};
  float s[4]  = {0.f, 0.f, 0.f, 0.f};
  float t[4]  = {0.f, 0.f, 0.f, 0.f};
#pragma unroll 4
  for (int i = 0; i < CH; ++i) {
    floatx4 v = xv[base + i * L4];
#pragma unroll
    for (int k = 0; k < 4; ++k) {
      float e = v[k] - mu[k];
      s[k] = fmaf(AFWD, s[k], e * e);
      t[k] += e;
      mu[k] = fmaf(ONE_MINUS_A, e, mu[k]);
    }
  }
  int o = c * L4 + col4;
  floatx4 om = {mu[0], mu[1], mu[2], mu[3]};
  floatx4 os = {s[0], s[1], s[2], s[3]};
  floatx4 ot = {t[0], t[1], t[2], t[3]};
  ((floatx4*)Bmu)[o] = om;
  ((floatx4*)See)[o] = os;
  ((floatx4*)Te)[o]  = ot;
}

// ---- pass C body: exact replay from (M_c,V_c) over one col-half ----
__device__ __forceinline__ void
passC_body(const float* __restrict__ x, const float* __restrict__ Ms,
           const float* __restrict__ Vs, float* __restrict__ out,
           int L4, int L4h, int CH, int colOff, int ih) {
  int col4 = colOff + (ih % L4h);
  int c    = ih / L4h;
  const floatx4* xv = (const floatx4*)x;
  floatx4* ov = (floatx4*)out;
  int base = c * CH * L4 + col4;

  int o = c * L4 + col4;
  floatx4 m4 = ((const floatx4*)Ms)[o];
  floatx4 v4 = ((const floatx4*)Vs)[o];
  float mu[4] = {m4[0], m4[1], m4[2], m4[3]};
  float vv[4] = {v4[0], v4[1], v4[2], v4[3]};
#pragma unroll 4
  for (int i = 0; i < CH; ++i) {
    floatx4 v = xv[base + i * L4];
    floatx4 oe;
#pragma unroll
    for (int k = 0; k < 4; ++k) {
      float d = v[k] - mu[k];
      oe[k] = d * rsqrtf(vv[k] + EPSV);
      vv[k] = fmaf(AFWD, vv[k], KCOEF * (d * d));
      mu[k] = fmaf(ONE_MINUS_A, d, mu[k]);
    }
    __builtin_nontemporal_store(oe, &ov[base + i * L4]);
  }
}

__global__ __launch_bounds__(256) void
kA(const float* __restrict__ x, float* __restrict__ Bmu,
   float* __restrict__ See, float* __restrict__ Te,
   int L4, int L4h, int CH, int colOff) {
  passA_body(x, Bmu, See, Te, L4, L4h, CH, colOff,
             blockIdx.x * 256 + threadIdx.x);
}

__global__ __launch_bounds__(256) void
kC(const float* __restrict__ x, const float* __restrict__ Ms,
   const float* __restrict__ Vs, float* __restrict__ out,
   int L4, int L4h, int CH, int colOff) {
  passC_body(x, Ms, Vs, out, L4, L4h, CH, colOff,
             blockIdx.x * 256 + threadIdx.x);
}

// ---- combined: blocks [0,HB) = C over half0 ; blocks [HB,2HB) = A half1 ----
__global__ __launch_bounds__(256) void
kCA(const float* __restrict__ x, const float* __restrict__ Ms,
    const float* __restrict__ Vs, float* __restrict__ out,
    float* __restrict__ Bmu, float* __restrict__ See, float* __restrict__ Te,
    int L4, int L4h, int CH, int HB) {
  if ((int)blockIdx.x < HB) {
    passC_body(x, Ms, Vs, out, L4, L4h, CH, 0,
               blockIdx.x * 256 + threadIdx.x);
  } else {
    passA_body(x, Bmu, See, Te, L4, L4h, CH, L4h,
               (blockIdx.x - HB) * 256 + threadIdx.x);
  }
}

// ---- pass B (proven R10): block = 8 super-chunk slots x 32 cols ----
__global__ __launch_bounds__(256) void
passBfused(const float* __restrict__ m, const float* __restrict__ var,
           const float* __restrict__ Bmu, const float* __restrict__ See,
           const float* __restrict__ Te, float* __restrict__ Ms,
           float* __restrict__ Vs, int L, int SUB, int GS, int colBase,
           float A, float c_eg, float Sgg, float G,
           float Asup, float c_sup, float Sggsup) {
  __shared__ float Bs[8][32], Ss[8][32], Ts[8][32];
  __shared__ float MgL[8][32], VgL[8][32];

  int g  = threadIdx.x >> 5;
  int lc = threadIdx.x & 31;
  int l  = colBase + blockIdx.x * 32 + lc;

  {
    int base = g * SUB * L + l;
    float B = 0.f, T = 0.f, S = 0.f;
#pragma unroll 4
    for (int k = 0; k < SUB; ++k) {
      int o = base + k * L;
      float b2 = Bmu[o];
      float s2 = See[o];
      float t2 = Te[o];
      S = fmaf(A, S, fmaf(Sgg * B, B, fmaf(-2.0f * c_eg * B, t2, s2)));
      T = fmaf(-G, B, T + t2);
      B = fmaf(A, B, b2);
    }
    Bs[g][lc] = B;
    Ss[g][lc] = S;
    Ts[g][lc] = T;
  }

  __syncthreads();

  if (threadIdx.x < 32) {
    float M = m[l];
    float V = var[l];
#pragma unroll
    for (int gg = 0; gg < 8; ++gg) {
      if (gg >= GS) break;
      MgL[gg][lc] = M;
      VgL[gg][lc] = V;
      float b = Bs[gg][lc];
      float s = Ss[gg][lc];
      float t = Ts[gg][lc];
      float sum = fmaf(M * M, Sggsup, fmaf(-2.0f * c_sup * M, t, s));
      V = fmaf(Asup, V, KCOEF * sum);
      M = fmaf(Asup, M, b);
    }
  }

  __syncthreads();

  {
    float M = MgL[g][lc];
    float V = VgL[g][lc];
    int base = g * SUB * L + l;
#pragma unroll 4
    for (int k = 0; k < SUB; ++k) {
      int o = base + k * L;
      Ms[o] = M;
      Vs[o] = V;
      float b = Bmu[o];
      float s = See[o];
      float t = Te[o];
      float sum = fmaf(M * M, Sgg, fmaf(-2.0f * c_eg * M, t, s));
      V = fmaf(A, V, KCOEF * sum);
      M = fmaf(A, M, b);
    }
  }
}

extern "C" void kernel_launch(void* const* d_in, const int* in_sizes, int n_in,
                              void* d_out, int out_size, void* d_ws, size_t ws_size,
                              hipStream_t stream) {
  const float* x   = (const float*)d_in[0];
  const float* m   = (const float*)d_in[1];
  const float* var = (const float*)d_in[2];
  float* out = (float*)d_out;

  int L  = in_sizes[1];          // 4096
  int N  = in_sizes[0] / L;      // 8192
  int L4 = L / 4;
  int L4h = L4 / 2;              // half the float4 columns
  int Lh  = L / 2;

  int C = 128;
  while (C > 1 &&
         ((size_t)5 * C * L * sizeof(float) > ws_size || (N % C) != 0))
    C >>= 1;
  int CH = N / C;
  int SUB = (C >= 16) ? 16 : C;
  int GS  = C / SUB;   // <= 8 for passBfused LDS

  double a = 0.999;
  float A    = (float)pow(a, (double)CH);
  float c_eg = (float)pow(a, (double)(CH - 1));
  float Sgg  = (float)(pow(a, (double)(CH - 1)) * (1.0 - pow(a, (double)CH)) / (1.0 - a));
  float G    = (float)((1.0 - pow(a, (double)CH)) / (1.0 - a));
  double nS = (double)SUB * CH;
  float Asup   = (float)pow(a, nS);
  float c_sup  = (float)pow(a, nS - 1.0);
  float Sggsup = (float)(pow(a, nS - 1.0) * (1.0 - pow(a, nS)) / (1.0 - a));

  float* ws  = (float*)d_ws;
  size_t CL  = (size_t)C * L;
  float* Bmu = ws;
  float* See = ws + CL;
  float* Te  = ws + 2 * CL;
  float* Ms  = ws + 3 * CL;
  float* Vs  = ws + 4 * CL;

  int HB = (C * L4h) / 256;      // blocks per half-pass (256)
  int BB = Lh / 32;              // passBfused blocks per half (64)

  // half 0
  kA<<<HB, 256, 0, stream>>>(x, Bmu, See, Te, L4, L4h, CH, 0);
  passBfused<<<BB, 256, 0, stream>>>(m, var, Bmu, See, Te, Ms, Vs, L, SUB, GS,
                                     0, A, c_eg, Sgg, G, Asup, c_sup, Sggsup);
  // C(half0) || A(half1) — disjoint columns, no dependency
  kCA<<<2 * HB, 256, 0, stream>>>(x, Ms, Vs, out, Bmu, See, Te, L4, L4h, CH,
                                  HB);
  // half 1
  passBfused<<<BB, 256, 0, stream>>>(m, var, Bmu, See, Te, Ms, Vs, L, SUB, GS,
                                     Lh, A, c_eg, Sgg, G, Asup, c_sup, Sggsup);
  kC<<<HB, 256, 0, stream>>>(x, Ms, Vs, out, L4, L4h, CH, L4h);
}